// Round 13
// baseline (166.282 us; speedup 1.0000x reference)
//
#include <hip/hip_runtime.h>
#include <stdint.h>

typedef unsigned short u16;
typedef __attribute__((ext_vector_type(8))) short short8;
typedef __attribute__((ext_vector_type(4))) float f32x4;

#define BATCH 4
#define SEQ   2048
#define DIN   768
#define DK    128
#define DV    768
#define MTOT  (BATCH*SEQ)   // 8192
#define NQKV  1024          // 128 q + 128 k + 768 v

__device__ __forceinline__ u16 f2bf(float f) {
  union { float f; uint32_t u; } v; v.f = f;
  uint32_t r = v.u + 0x7FFFu + ((v.u >> 16) & 1u);
  return (u16)(r >> 16);
}

template<int N> __device__ __forceinline__ void wait_vmcnt() {
  if constexpr (N == 0) asm volatile("s_waitcnt vmcnt(0)" ::: "memory");
}
__device__ __forceinline__ void wait_lgkm0() {
  asm volatile("s_waitcnt lgkmcnt(0)" ::: "memory");
}

#define GLOAD_LDS(SRC, DST) \
  __builtin_amdgcn_global_load_lds( \
      (const __attribute__((address_space(1))) unsigned int*)(SRC), \
      (__attribute__((address_space(3))) unsigned int*)(DST), 16, 0, 0)

// ---------------- K0: prep = convert_x + pack weights/bias ----------------
__global__ __launch_bounds__(256) void prep(
    const float* __restrict__ x, u16* __restrict__ xb,
    const float* __restrict__ Wq, const float* __restrict__ bq,
    const float* __restrict__ Wk, const float* __restrict__ bk,
    const float* __restrict__ Wv, const float* __restrict__ bv,
    u16* __restrict__ WbT, float* __restrict__ biasP) {
  const float qs = 0.088388347648318447f;  // 1/sqrt(128)
  __shared__ u16 tile[64][72];
  int b = blockIdx.x;
  int tid = threadIdx.x;
  if (b < 6144) {               // convert x -> bf16
    int i = (b * 256 + tid) * 4;
    float4 v = *(const float4*)(x + i);
    u16 o[4] = { f2bf(v.x), f2bf(v.y), f2bf(v.z), f2bf(v.w) };
    *(uint2*)(xb + i) = *(const uint2*)o;
    return;
  }
  int bid2 = b - 6144;          // 0..191 : pack weights (12 x 16)
  int y   = bid2 / 12;
  int i0  = (bid2 - y * 12) * 64;
  const float* W; u16* dst; int ldw, nb; float sc;
  if (y < 2)      { W = Wq; dst = WbT;                      ldw = DK; sc = qs;   nb = y;     }
  else if (y < 4) { W = Wk; dst = WbT + (size_t)DK * DIN;   ldw = DK; sc = 1.0f; nb = y - 2; }
  else            { W = Wv; dst = WbT + (size_t)2*DK * DIN; ldw = DV; sc = 1.0f; nb = y - 4; }
  int n0 = nb * 64;
  if (i0 == 0 && y == 0) {
    for (int n = tid; n < NQKV; n += 256)
      biasP[n] = (n < DK) ? bq[n] * qs : (n < 2*DK ? bk[n - DK] : bv[n - 2*DK]);
  }
  int tr = tid >> 2;
  int tc = (tid & 3) * 16;
  const float* src = W + (size_t)(i0 + tr) * ldw + n0 + tc;
  u16 o[16];
#pragma unroll
  for (int u = 0; u < 16; u += 4) {
    float4 v = *(const float4*)(src + u);
    o[u] = f2bf(v.x * sc); o[u+1] = f2bf(v.y * sc); o[u+2] = f2bf(v.z * sc); o[u+3] = f2bf(v.w * sc);
  }
  *(uint4*)&tile[tr][tc]     = *(const uint4*)&o[0];
  *(uint4*)&tile[tr][tc + 8] = *(const uint4*)&o[8];
  __syncthreads();
  u16 tmp[16];
#pragma unroll
  for (int u = 0; u < 16; ++u) tmp[u] = tile[tc + u][tr];
  u16* d = dst + (size_t)(n0 + tr) * DIN + i0 + tc;
  *(uint4*)d       = *(const uint4*)&tmp[0];
  *(uint4*)(d + 8) = *(const uint4*)&tmp[8];
}

// ---------------- proj GEMM (2-phase dbuf): qkv projection ----------------
__global__ __launch_bounds__(512, 4) void gemm_proj(
    const u16* __restrict__ A, const u16* __restrict__ BT,
    u16* __restrict__ C0, u16* __restrict__ C1,
    const float* __restrict__ bias)
{
  const int NJ = 2, CH = 4, gx = 64;
  __shared__ u16 As[2][128][64];
  __shared__ u16 Bs[2][NJ * 64][64];
  const int tid = threadIdx.x;
  const int l   = tid & 63;
  const int wid = tid >> 6;
  const int wm  = wid >> 2;
  const int wn  = wid & 3;

  const int nwg = gridDim.x;
  const int cpx = nwg >> 3;
  const int bid = blockIdx.x;
  const int wg  = (bid & 7) * cpx + (bid >> 3);
  const int by  = wg / gx;
  const int bx  = wg - by * gx;
  const int m0  = bx * 128;
  const int n0  = by * (NJ * 64);

  f32x4 acc[4][NJ] = {};
  const int lr = l >> 3;
  const int lc = ((l & 7) ^ lr) * 8;
  const int ca = wid * CH;

  auto STAGE = [&](int buf, int k0) {
#pragma unroll
    for (int i = 0; i < CH; ++i) {
      int c = ca + i;
      if (c < 16) {
        GLOAD_LDS(A + (size_t)(m0 + c * 8 + lr) * DIN + k0 + lc, &As[buf][c * 8][0]);
      } else {
        int cb = c - 16;
        GLOAD_LDS(BT + (size_t)(n0 + cb * 8 + lr) * DIN + k0 + lc, &Bs[buf][cb * 8][0]);
      }
    }
  };

  STAGE(0, 0);
  __syncthreads();
  int cur = 0;
  for (int k0 = 0; k0 < DIN; k0 += 64) {
    if (k0 + 64 < DIN) STAGE(cur ^ 1, k0 + 64);
#pragma unroll
    for (int ks = 0; ks < 2; ++ks) {
      short8 af[4], bg[NJ];
#pragma unroll
      for (int i = 0; i < 4; ++i) {
        int row  = wm * 64 + i * 16 + (l & 15);
        int slot = (ks * 4 + (l >> 4)) ^ (row & 7);
        af[i] = *(const short8*)&As[cur][row][slot * 8];
      }
#pragma unroll
      for (int j = 0; j < NJ; ++j) {
        int row  = wn * (NJ * 16) + j * 16 + (l & 15);
        int slot = (ks * 4 + (l >> 4)) ^ (row & 7);
        bg[j] = *(const short8*)&Bs[cur][row][slot * 8];
      }
#pragma unroll
      for (int i = 0; i < 4; ++i)
#pragma unroll
        for (int j = 0; j < NJ; ++j)
          acc[i][j] = __builtin_amdgcn_mfma_f32_16x16x32_bf16(af[i], bg[j], acc[i][j], 0, 0, 0);
    }
    __syncthreads();
    cur ^= 1;
  }

  const int rbase = (l >> 4) * 4;
  const int cl    = l & 15;
#pragma unroll
  for (int i = 0; i < 4; ++i) {
#pragma unroll
    for (int j = 0; j < NJ; ++j) {
      int col = n0 + wn * (NJ * 16) + j * 16 + cl;
      int row0 = m0 + wm * 64 + i * 16 + rbase;
      float bv_ = bias[col];
      if (n0 < 256) {
#pragma unroll
        for (int q = 0; q < 4; ++q)
          C0[(size_t)(row0 + q) * 256 + col] = f2bf(acc[i][j][q] + bv_);
      } else {
        int b = row0 >> 11, t = row0 & 2047;
        u16 o[4];
#pragma unroll
        for (int q = 0; q < 4; ++q) o[q] = f2bf(acc[i][j][q] + bv_);
        *(uint2*)&C1[((size_t)b * DV + (col - 256)) * SEQ + t] = *(const uint2*)o;
      }
    }
  }
}

// ---------------- K3: S-GEMM single-stage: P = exp(q_s @ k^T), bf16 out ----------------
__global__ __launch_bounds__(512, 4) void sgemm_exp(
    const u16* __restrict__ qk, u16* __restrict__ P)
{
  __shared__ u16 As[128][128];
  __shared__ u16 Bs[128][128];
  const int tid = threadIdx.x;
  const int l   = tid & 63;
  const int wid = tid >> 6;
  const int wm  = wid >> 2;
  const int wn  = wid & 3;

  const int nwg = gridDim.x;      // 1024
  const int cpx = nwg >> 3;
  const int bid = blockIdx.x;
  const int wg  = (bid & 7) * cpx + (bid >> 3);
  const int z   = wg >> 8;
  const int rem = wg & 255;
  const int by  = rem >> 4;
  const int bx  = rem & 15;
  const int m0  = bx * 128;
  const int n0  = by * 128;

  const u16* A  = qk + (size_t)z * SEQ * 256;
  const u16* BT = qk + DK + (size_t)z * SEQ * 256;

  const int rin  = l >> 4;
  const int s16  = l & 15;
#pragma unroll
  for (int i = 0; i < 8; ++i) {
    int c = wid * 8 + i;
    if (c < 32) {
      int r = c * 4 + rin;
      int gs = s16 ^ (r & 7);
      GLOAD_LDS(A + (size_t)(m0 + r) * 256 + gs * 8, &As[c * 4][0]);
    } else {
      int cb = c - 32;
      int r = cb * 4 + rin;
      int gs = s16 ^ (r & 7);
      GLOAD_LDS(BT + (size_t)(n0 + r) * 256 + gs * 8, &Bs[cb * 4][0]);
    }
  }
  __syncthreads();

  f32x4 acc[4][2] = {};
#pragma unroll
  for (int ks = 0; ks < 4; ++ks) {
    short8 af[4], bg[2];
#pragma unroll
    for (int i = 0; i < 4; ++i) {
      int row  = wm * 64 + i * 16 + (l & 15);
      int slot = (ks * 4 + (l >> 4)) ^ (row & 7);
      af[i] = *(const short8*)&As[row][slot * 8];
    }
#pragma unroll
    for (int j = 0; j < 2; ++j) {
      int row  = wn * 32 + j * 16 + (l & 15);
      int slot = (ks * 4 + (l >> 4)) ^ (row & 7);
      bg[j] = *(const short8*)&Bs[row][slot * 8];
    }
#pragma unroll
    for (int i = 0; i < 4; ++i)
#pragma unroll
      for (int j = 0; j < 2; ++j)
        acc[i][j] = __builtin_amdgcn_mfma_f32_16x16x32_bf16(af[i], bg[j], acc[i][j], 0, 0, 0);
  }

  const int rbase = (l >> 4) * 4;
  const int cl    = l & 15;
  u16* Pz = P + (size_t)z * SEQ * SEQ;
#pragma unroll
  for (int i = 0; i < 4; ++i)
#pragma unroll
    for (int j = 0; j < 2; ++j) {
      int col  = n0 + wn * 32 + j * 16 + cl;
      int row0 = m0 + wm * 64 + i * 16 + rbase;
#pragma unroll
      for (int q = 0; q < 4; ++q)
        Pz[(size_t)(row0 + q) * SEQ + col] = f2bf(__expf(acc[i][j][q]));
    }
}

// ---------------- PV GEMM: 128x192 tile, REG-STAGED (T14) 2-slot dbuf ----------------
// out = (P @ vT^T) / rowsum(P); rowsum via ones-MFMA.
// Hypothesis test: staging via global_load_dwordx4 -> VGPR -> ds_write_b128
// (bypasses the ~14 B/cyc/CU global_load_lds path). Loads for tile t+1 are
// issued one full compute-phase early; write-late after vmcnt(0). One barrier
// per K-tile. Swizzle on the ds_write address (slot = (l&7)^lr), read unchanged.
// by-fastest XCD decode: the 4 blocks sharing a P panel run on one XCD (L2 reuse).
__global__ __launch_bounds__(512, 2) void gemm_pv(
    const u16* __restrict__ P, const u16* __restrict__ vT,
    float* __restrict__ out)
{
  const int NT = SEQ / 64;             // 32 K-tiles
  __shared__ u16 As[2][128][64];       // 32 KB
  __shared__ u16 Bs[2][192][64];       // 48 KB
  const int tid = threadIdx.x;
  const int l   = tid & 63;
  const int wid = tid >> 6;
  const int wm  = wid >> 2;            // 0..1 : 64-row group
  const int wn  = wid & 3;             // 0..3 : 48-col group

  const int nwg = gridDim.x;           // 256
  const int cpx = nwg >> 3;
  const int bid = blockIdx.x;
  const int wg  = (bid & 7) * cpx + (bid >> 3);
  const int z   = wg >> 6;
  const int rem = wg & 63;
  const int by  = rem & 3;             // by fastest -> P-panel sharing within XCD
  const int bx  = rem >> 2;
  const int m0  = bx * 128;
  const int nv0 = by * 192;

  const u16* A  = P  + (size_t)z * SEQ * SEQ;
  const u16* BT = vT + (size_t)z * DV * SEQ;

  f32x4 acc[4][3] = {};
  f32x4 accO[4] = {};
  const short8 kOnes = {16256,16256,16256,16256,16256,16256,16256,16256};

  const int lr   = l >> 3;             // row within 8-row chunk
  const int cole = (l & 7) * 8;        // linear global column slot
  const int swz  = ((l & 7) ^ lr) * 8; // swizzled LDS slot
  const int ca   = wid * 5;            // 40 chunks: 0..15 A, 16..39 B

  uint4 rg[5];

  auto LOADR = [&](int k0) {
#pragma unroll
    for (int i = 0; i < 5; ++i) {
      int c = ca + i;
      const u16* src = (c < 16)
          ? A  + (size_t)(m0  + c * 8 + lr) * SEQ + k0 + cole
          : BT + (size_t)(nv0 + (c - 16) * 8 + lr) * SEQ + k0 + cole;
      rg[i] = *(const uint4*)src;
    }
  };
  auto WRITE = [&](int buf) {
#pragma unroll
    for (int i = 0; i < 5; ++i) {
      int c = ca + i;
      if (c < 16) *(uint4*)&As[buf][c * 8 + lr][swz] = rg[i];
      else        *(uint4*)&Bs[buf][(c - 16) * 8 + lr][swz] = rg[i];
    }
  };
  auto COMPUTE = [&](int buf) {
#pragma unroll
    for (int ks = 0; ks < 2; ++ks) {
      short8 af[4], bg[3];
#pragma unroll
      for (int i = 0; i < 4; ++i) {
        int row  = wm * 64 + i * 16 + (l & 15);
        int slot = (ks * 4 + (l >> 4)) ^ (row & 7);
        af[i] = *(const short8*)&As[buf][row][slot * 8];
      }
#pragma unroll
      for (int j = 0; j < 3; ++j) {
        int row  = wn * 48 + j * 16 + (l & 15);
        int slot = (ks * 4 + (l >> 4)) ^ (row & 7);
        bg[j] = *(const short8*)&Bs[buf][row][slot * 8];
      }
      __builtin_amdgcn_s_setprio(1);
#pragma unroll
      for (int i = 0; i < 4; ++i) {
#pragma unroll
        for (int j = 0; j < 3; ++j)
          acc[i][j] = __builtin_amdgcn_mfma_f32_16x16x32_bf16(af[i], bg[j], acc[i][j], 0, 0, 0);
        accO[i] = __builtin_amdgcn_mfma_f32_16x16x32_bf16(af[i], kOnes, accO[i], 0, 0, 0);
      }
      __builtin_amdgcn_s_setprio(0);
    }
  };

  LOADR(0);
  wait_vmcnt<0>();
  WRITE(0);
  LOADR(64);                           // tile 1 in flight across tile-0 compute
  wait_lgkm0();
  __builtin_amdgcn_s_barrier();

  int cur = 0;
  for (int t = 0; t < NT; ++t) {
    COMPUTE(cur);
    if (t + 1 < NT) {
      wait_vmcnt<0>();                 // tile t+1 regs arrived
      WRITE(cur ^ 1);
      wait_lgkm0();                    // my ds_writes done (frees rg)
      if (t + 2 < NT) LOADR((t + 2) * 64);  // issue early: covered by next COMPUTE
      __builtin_amdgcn_s_barrier();    // writes visible + all done reading cur
    }
    cur ^= 1;
  }

  const int rbase = (l >> 4) * 4;
  const int cl    = l & 15;
#pragma unroll
  for (int i = 0; i < 4; ++i) {
    int row0 = m0 + wm * 64 + i * 16 + rbase;
    f32x4 rs;
#pragma unroll
    for (int q = 0; q < 4; ++q) rs[q] = 1.0f / accO[i][q];
#pragma unroll
    for (int j = 0; j < 3; ++j) {
      int col = nv0 + wn * 48 + j * 16 + cl;
#pragma unroll
      for (int q = 0; q < 4; ++q)
        out[(size_t)z * SEQ * DV + (size_t)(row0 + q) * DV + col] = acc[i][j][q] * rs[q];
    }
  }
}

extern "C" void kernel_launch(void* const* d_in, const int* in_sizes, int n_in,
                              void* d_out, int out_size, void* d_ws, size_t ws_size,
                              hipStream_t stream) {
  const float* x  = (const float*)d_in[0];
  const float* Wq = (const float*)d_in[1];
  const float* bq = (const float*)d_in[2];
  const float* Wk = (const float*)d_in[3];
  const float* bk = (const float*)d_in[4];
  const float* Wv = (const float*)d_in[5];
  const float* bv = (const float*)d_in[6];
  float* out = (float*)d_out;

  size_t off = 0;
  auto alloc = [&](size_t bytes) -> void* {
    void* p = (char*)d_ws + off;
    off += (bytes + 255) & ~(size_t)255;
    return p;
  };
  u16*   xb    = (u16*)alloc((size_t)MTOT * DIN * 2);
  u16*   WbT   = (u16*)alloc((size_t)NQKV * DIN * 2);
  float* biasP = (float*)alloc(NQKV * 4);
  u16*   qk    = (u16*)alloc((size_t)MTOT * 256 * 2);
  u16*   vT    = (u16*)alloc((size_t)BATCH * DV * SEQ * 2);
  u16*   P     = (u16*)alloc((size_t)BATCH * SEQ * SEQ * 2);
  if (off > ws_size) return;

  prep<<<dim3(6144 + 192), dim3(256), 0, stream>>>(x, xb, Wq, bq, Wk, bk, Wv, bv, WbT, biasP);

  // proj: [8192,1024] = xb @ WbT^T + bias; writes qk (n<256) and vT (transposed)
  gemm_proj<<<dim3(64 * 8), dim3(512), 0, stream>>>(xb, WbT, qk, vT, biasP);

  // P = exp(q_scaled @ k^T) per batch (M=N=2048, K=128), single-stage
  sgemm_exp<<<dim3(16 * 16 * BATCH), dim3(512), 0, stream>>>(qk, P);

  // out = (P @ vT^T) / rowsum(P) per batch, 128x192 tile, reg-staged pipeline
  gemm_pv<<<dim3(16 * 4 * BATCH), dim3(512), 0, stream>>>(P, vT, out);
}

// Round 14
// 83.188 us; speedup vs baseline: 1.9989x; 1.9989x over previous
//
#include <hip/hip_runtime.h>
#include <stdint.h>

typedef unsigned short u16;
typedef __attribute__((ext_vector_type(8))) short short8;
typedef __attribute__((ext_vector_type(4))) float f32x4;

#define BATCH 4
#define SEQ   2048
#define DIN   768
#define DK    128
#define DV    768
#define MTOT  (BATCH*SEQ)   // 8192
#define NQKV  1024          // 128 q + 128 k + 768 v

__device__ __forceinline__ u16 f2bf(float f) {
  union { float f; uint32_t u; } v; v.f = f;
  uint32_t r = v.u + 0x7FFFu + ((v.u >> 16) & 1u);
  return (u16)(r >> 16);
}

template<int N> __device__ __forceinline__ void wait_vmcnt() {
  if constexpr (N == 0) asm volatile("s_waitcnt vmcnt(0)" ::: "memory");
  else if constexpr (N == 5) asm volatile("s_waitcnt vmcnt(5)" ::: "memory");
  else if constexpr (N == 6) asm volatile("s_waitcnt vmcnt(6)" ::: "memory");
}

#define GLOAD_LDS(SRC, DST) \
  __builtin_amdgcn_global_load_lds( \
      (const __attribute__((address_space(1))) unsigned int*)(SRC), \
      (__attribute__((address_space(3))) unsigned int*)(DST), 16, 0, 0)

// ---------------- K0: prep = convert_x + pack weights/bias ----------------
__global__ __launch_bounds__(256) void prep(
    const float* __restrict__ x, u16* __restrict__ xb,
    const float* __restrict__ Wq, const float* __restrict__ bq,
    const float* __restrict__ Wk, const float* __restrict__ bk,
    const float* __restrict__ Wv, const float* __restrict__ bv,
    u16* __restrict__ WbT, float* __restrict__ biasP) {
  const float qs = 0.088388347648318447f;  // 1/sqrt(128)
  __shared__ u16 tile[64][72];
  int b = blockIdx.x;
  int tid = threadIdx.x;
  if (b < 6144) {               // convert x -> bf16
    int i = (b * 256 + tid) * 4;
    float4 v = *(const float4*)(x + i);
    u16 o[4] = { f2bf(v.x), f2bf(v.y), f2bf(v.z), f2bf(v.w) };
    *(uint2*)(xb + i) = *(const uint2*)o;
    return;
  }
  int bid2 = b - 6144;          // 0..191 : pack weights (12 x 16)
  int y   = bid2 / 12;
  int i0  = (bid2 - y * 12) * 64;
  const float* W; u16* dst; int ldw, nb; float sc;
  if (y < 2)      { W = Wq; dst = WbT;                      ldw = DK; sc = qs;   nb = y;     }
  else if (y < 4) { W = Wk; dst = WbT + (size_t)DK * DIN;   ldw = DK; sc = 1.0f; nb = y - 2; }
  else            { W = Wv; dst = WbT + (size_t)2*DK * DIN; ldw = DV; sc = 1.0f; nb = y - 4; }
  int n0 = nb * 64;
  if (i0 == 0 && y == 0) {
    for (int n = tid; n < NQKV; n += 256)
      biasP[n] = (n < DK) ? bq[n] * qs : (n < 2*DK ? bk[n - DK] : bv[n - 2*DK]);
  }
  int tr = tid >> 2;
  int tc = (tid & 3) * 16;
  const float* src = W + (size_t)(i0 + tr) * ldw + n0 + tc;
  u16 o[16];
#pragma unroll
  for (int u = 0; u < 16; u += 4) {
    float4 v = *(const float4*)(src + u);
    o[u] = f2bf(v.x * sc); o[u+1] = f2bf(v.y * sc); o[u+2] = f2bf(v.z * sc); o[u+3] = f2bf(v.w * sc);
  }
  *(uint4*)&tile[tr][tc]     = *(const uint4*)&o[0];
  *(uint4*)&tile[tr][tc + 8] = *(const uint4*)&o[8];
  __syncthreads();
  u16 tmp[16];
#pragma unroll
  for (int u = 0; u < 16; ++u) tmp[u] = tile[tc + u][tr];
  u16* d = dst + (size_t)(n0 + tr) * DIN + i0 + tc;
  *(uint4*)d       = *(const uint4*)&tmp[0];
  *(uint4*)(d + 8) = *(const uint4*)&tmp[8];
}

// ---------------- proj GEMM: 128x256 tile, 3-slot counted-vmcnt(6) ring ----------------
// qkv projection: by==0 -> qk bf16 [M][256]; by>=1 -> vT bf16 [BATCH][DV][SEQ] TRANSPOSED.
// 8 waves = 2 row-halves x 4 col-quarters; acc[4][4]. LDS 144KB, 1 block/CU.
__global__ __launch_bounds__(512, 2) void gemm_proj(
    const u16* __restrict__ A, const u16* __restrict__ BT,
    u16* __restrict__ C0, u16* __restrict__ C1,
    const float* __restrict__ bias)
{
  const int NT = DIN / 64;             // 12 K-tiles
  __shared__ u16 As[3][128][64];       // 48 KB
  __shared__ u16 Bs[3][256][64];       // 96 KB
  const int tid = threadIdx.x;
  const int l   = tid & 63;
  const int wid = tid >> 6;
  const int wm  = wid >> 2;            // 0..1 : 64-row half
  const int wn  = wid & 3;             // 0..3 : 64-col quarter

  const int nwg = gridDim.x;           // 256
  const int cpx = nwg >> 3;
  const int bid = blockIdx.x;
  const int wg  = (bid & 7) * cpx + (bid >> 3);
  const int by  = wg >> 6;             // 0..3 (XCD chunk shares B panel)
  const int bx  = wg & 63;
  const int m0  = bx * 128;
  const int n0  = by * 256;

  f32x4 acc[4][4] = {};
  const int lr = l >> 3;
  const int lc = ((l & 7) ^ lr) * 8;

  // 48 chunks: 0..15 A rows, 16..47 B rows; 6 per wave
  auto STAGE = [&](int buf, int k0, int i0r, int i1r) {
#pragma unroll
    for (int i = 0; i < 6; ++i) {
      if (i < i0r || i >= i1r) continue;
      int c = wid * 6 + i;
      if (c < 16) {
        GLOAD_LDS(A + (size_t)(m0 + c * 8 + lr) * DIN + k0 + lc, &As[buf][c * 8][0]);
      } else {
        int cb = c - 16;
        GLOAD_LDS(BT + (size_t)(n0 + cb * 8 + lr) * DIN + k0 + lc, &Bs[buf][cb * 8][0]);
      }
    }
  };

  STAGE(0, 0, 0, 6);
  STAGE(1, 64, 0, 6);
  int cur = 0;
  for (int t = 0; t < NT; ++t) {
    if (t == NT - 1) wait_vmcnt<0>(); else wait_vmcnt<6>();
    __builtin_amdgcn_s_barrier();
    const int nxt2 = (cur + 2 >= 3) ? cur - 1 : cur + 2;
    const bool pf = (t + 2 < NT);
#pragma unroll
    for (int ks = 0; ks < 2; ++ks) {
      short8 af[4], bg[4];
#pragma unroll
      for (int i = 0; i < 4; ++i) {
        int row  = wm * 64 + i * 16 + (l & 15);
        int slot = (ks * 4 + (l >> 4)) ^ (row & 7);
        af[i] = *(const short8*)&As[cur][row][slot * 8];
      }
#pragma unroll
      for (int j = 0; j < 4; ++j) {
        int row  = wn * 64 + j * 16 + (l & 15);
        int slot = (ks * 4 + (l >> 4)) ^ (row & 7);
        bg[j] = *(const short8*)&Bs[cur][row][slot * 8];
      }
      if (pf) {
        if (ks == 0) STAGE(nxt2, (t + 2) * 64, 0, 3);
        else         STAGE(nxt2, (t + 2) * 64, 3, 6);
      }
      __builtin_amdgcn_s_setprio(1);
#pragma unroll
      for (int i = 0; i < 4; ++i)
#pragma unroll
        for (int j = 0; j < 4; ++j)
          acc[i][j] = __builtin_amdgcn_mfma_f32_16x16x32_bf16(af[i], bg[j], acc[i][j], 0, 0, 0);
      __builtin_amdgcn_s_setprio(0);
    }
    cur = (cur + 1 == 3) ? 0 : cur + 1;
  }

  const int rbase = (l >> 4) * 4;
  const int cl    = l & 15;
#pragma unroll
  for (int i = 0; i < 4; ++i) {
#pragma unroll
    for (int j = 0; j < 4; ++j) {
      int col  = n0 + wn * 64 + j * 16 + cl;
      int row0 = m0 + wm * 64 + i * 16 + rbase;
      float bv_ = bias[col];
      if (by == 0) {
#pragma unroll
        for (int q = 0; q < 4; ++q)
          C0[(size_t)(row0 + q) * 256 + col] = f2bf(acc[i][j][q] + bv_);
      } else {
        int b = row0 >> 11, t = row0 & 2047;
        u16 o[4];
#pragma unroll
        for (int q = 0; q < 4; ++q) o[q] = f2bf(acc[i][j][q] + bv_);
        *(uint2*)&C1[((size_t)b * DV + (col - 256)) * SEQ + t] = *(const uint2*)o;
      }
    }
  }
}

// ---------------- K3: S-GEMM 256x256 single-stage: P = exp(q_s @ k^T), bf16 out ----------------
// Whole K=128 staged at once: As/Bs 256x128 = 128KB LDS, one barrier, 128 MFMA/wave.
__global__ __launch_bounds__(512, 2) void sgemm_exp(
    const u16* __restrict__ qk, u16* __restrict__ P)
{
  __shared__ u16 As[256][128];
  __shared__ u16 Bs[256][128];
  const int tid = threadIdx.x;
  const int l   = tid & 63;
  const int wid = tid >> 6;
  const int wm  = wid >> 2;            // 0..1 : 128-row half
  const int wn  = wid & 3;             // 0..3 : 64-col quarter

  const int nwg = gridDim.x;           // 256
  const int cpx = nwg >> 3;
  const int bid = blockIdx.x;
  const int wg  = (bid & 7) * cpx + (bid >> 3);
  const int z   = wg >> 6;
  const int rem = wg & 63;
  const int by  = rem >> 3;
  const int bx  = rem & 7;
  const int m0  = bx * 256;
  const int n0  = by * 256;

  const u16* A  = qk + (size_t)z * SEQ * 256;
  const u16* BT = qk + DK + (size_t)z * SEQ * 256;

  const int rin = l >> 4;
  const int s16 = l & 15;
  // 128 chunks of 4 rows x 256B: 0..63 A, 64..127 B; 16 per wave
#pragma unroll
  for (int i = 0; i < 16; ++i) {
    int c = wid * 16 + i;
    if (c < 64) {
      int r = c * 4 + rin;
      int gs = s16 ^ (r & 7);
      GLOAD_LDS(A + (size_t)(m0 + r) * 256 + gs * 8, &As[c * 4][0]);
    } else {
      int cb = c - 64;
      int r = cb * 4 + rin;
      int gs = s16 ^ (r & 7);
      GLOAD_LDS(BT + (size_t)(n0 + r) * 256 + gs * 8, &Bs[cb * 4][0]);
    }
  }
  __syncthreads();

  f32x4 acc[8][4] = {};
#pragma unroll
  for (int ks = 0; ks < 4; ++ks) {
    short8 af[8], bg[4];
#pragma unroll
    for (int i = 0; i < 8; ++i) {
      int row  = wm * 128 + i * 16 + (l & 15);
      int slot = (ks * 4 + (l >> 4)) ^ (row & 7);
      af[i] = *(const short8*)&As[row][slot * 8];
    }
#pragma unroll
    for (int j = 0; j < 4; ++j) {
      int row  = wn * 64 + j * 16 + (l & 15);
      int slot = (ks * 4 + (l >> 4)) ^ (row & 7);
      bg[j] = *(const short8*)&Bs[row][slot * 8];
    }
#pragma unroll
    for (int i = 0; i < 8; ++i)
#pragma unroll
      for (int j = 0; j < 4; ++j)
        acc[i][j] = __builtin_amdgcn_mfma_f32_16x16x32_bf16(af[i], bg[j], acc[i][j], 0, 0, 0);
  }

  const int rbase = (l >> 4) * 4;
  const int cl    = l & 15;
  u16* Pz = P + (size_t)z * SEQ * SEQ;
#pragma unroll
  for (int i = 0; i < 8; ++i)
#pragma unroll
    for (int j = 0; j < 4; ++j) {
      int col  = n0 + wn * 64 + j * 16 + cl;
      int row0 = m0 + wm * 128 + i * 16 + rbase;
#pragma unroll
      for (int q = 0; q < 4; ++q)
        Pz[(size_t)(row0 + q) * SEQ + col] = f2bf(__expf(acc[i][j][q]));
    }
}

// ---------------- PV GEMM: 128x192, 3-slot ring, vmcnt(5), fine phases + setprio ----------------
// out = (P @ vT^T) / rowsum(P); rowsum via ones-MFMA. (r8-proven, 40.6us)
__global__ __launch_bounds__(512, 2) void gemm_pv(
    const u16* __restrict__ P, const u16* __restrict__ vT,
    float* __restrict__ out)
{
  const int NJ = 3, CH = 5, gx = 16, gy = 4, NT = SEQ / 64;  // 32 K-tiles
  __shared__ u16 As[3][128][64];       // 48 KB
  __shared__ u16 Bs[3][NJ * 64][64];   // 72 KB
  const int tid = threadIdx.x;
  const int l   = tid & 63;
  const int wid = tid >> 6;
  const int wm  = wid >> 2;
  const int wn  = wid & 3;

  const int nwg = gridDim.x;           // 256
  const int cpx = nwg >> 3;
  const int bid = blockIdx.x;
  const int wg  = (bid & 7) * cpx + (bid >> 3);
  const int z   = wg / (gx * gy);
  const int rem = wg - z * gx * gy;
  const int by  = rem / gx;
  const int bx  = rem - by * gx;
  const int m0  = bx * 128;
  const int n0  = by * (NJ * 64);

  const u16* A  = P  + (size_t)z * SEQ * SEQ;
  const u16* BT = vT + (size_t)z * DV * SEQ;

  f32x4 acc[4][NJ] = {};
  f32x4 accO[4] = {};
  const short8 kOnes = {16256,16256,16256,16256,16256,16256,16256,16256};

  const int lr = l >> 3;
  const int lc = ((l & 7) ^ lr) * 8;
  const int ca = wid * CH;

  auto STAGE = [&](int buf, int k0, int i0, int i1) {
#pragma unroll
    for (int i = 0; i < CH; ++i) {
      if (i < i0 || i >= i1) continue;
      int c = ca + i;
      if (c < 16) {
        GLOAD_LDS(A + (size_t)(m0 + c * 8 + lr) * SEQ + k0 + lc, &As[buf][c * 8][0]);
      } else {
        int cb = c - 16;
        GLOAD_LDS(BT + (size_t)(n0 + cb * 8 + lr) * SEQ + k0 + lc, &Bs[buf][cb * 8][0]);
      }
    }
  };

  STAGE(0, 0, 0, CH);
  STAGE(1, 64, 0, CH);
  int cur = 0;
  for (int t = 0; t < NT; ++t) {
    if (t == NT - 1) wait_vmcnt<0>(); else wait_vmcnt<CH>();
    __builtin_amdgcn_s_barrier();
    const int nxt2 = (cur + 2 >= 3) ? cur - 1 : cur + 2;
    const bool pf = (t + 2 < NT);
#pragma unroll
    for (int ks = 0; ks < 2; ++ks) {
      short8 af[4], bg[NJ];
#pragma unroll
      for (int i = 0; i < 4; ++i) {
        int row  = wm * 64 + i * 16 + (l & 15);
        int slot = (ks * 4 + (l >> 4)) ^ (row & 7);
        af[i] = *(const short8*)&As[cur][row][slot * 8];
      }
#pragma unroll
      for (int j = 0; j < NJ; ++j) {
        int row  = wn * (NJ * 16) + j * 16 + (l & 15);
        int slot = (ks * 4 + (l >> 4)) ^ (row & 7);
        bg[j] = *(const short8*)&Bs[cur][row][slot * 8];
      }
      if (pf) {
        if (ks == 0) STAGE(nxt2, (t + 2) * 64, 0, 3);
        else         STAGE(nxt2, (t + 2) * 64, 3, CH);
      }
      __builtin_amdgcn_s_setprio(1);
#pragma unroll
      for (int i = 0; i < 4; ++i) {
#pragma unroll
        for (int j = 0; j < NJ; ++j)
          acc[i][j] = __builtin_amdgcn_mfma_f32_16x16x32_bf16(af[i], bg[j], acc[i][j], 0, 0, 0);
        accO[i] = __builtin_amdgcn_mfma_f32_16x16x32_bf16(af[i], kOnes, accO[i], 0, 0, 0);
      }
      __builtin_amdgcn_s_setprio(0);
    }
    cur = (cur + 1 == 3) ? 0 : cur + 1;
  }

  const int rbase = (l >> 4) * 4;
  const int cl    = l & 15;
#pragma unroll
  for (int i = 0; i < 4; ++i) {
    int row0 = m0 + wm * 64 + i * 16 + rbase;
    f32x4 rs;
#pragma unroll
    for (int q = 0; q < 4; ++q) rs[q] = 1.0f / accO[i][q];
#pragma unroll
    for (int j = 0; j < NJ; ++j) {
      int col = n0 + wn * (NJ * 16) + j * 16 + cl;
#pragma unroll
      for (int q = 0; q < 4; ++q)
        out[(size_t)z * SEQ * DV + (size_t)(row0 + q) * DV + col] = acc[i][j][q] * rs[q];
    }
  }
}

extern "C" void kernel_launch(void* const* d_in, const int* in_sizes, int n_in,
                              void* d_out, int out_size, void* d_ws, size_t ws_size,
                              hipStream_t stream) {
  const float* x  = (const float*)d_in[0];
  const float* Wq = (const float*)d_in[1];
  const float* bq = (const float*)d_in[2];
  const float* Wk = (const float*)d_in[3];
  const float* bk = (const float*)d_in[4];
  const float* Wv = (const float*)d_in[5];
  const float* bv = (const float*)d_in[6];
  float* out = (float*)d_out;

  size_t off = 0;
  auto alloc = [&](size_t bytes) -> void* {
    void* p = (char*)d_ws + off;
    off += (bytes + 255) & ~(size_t)255;
    return p;
  };
  u16*   xb    = (u16*)alloc((size_t)MTOT * DIN * 2);
  u16*   WbT   = (u16*)alloc((size_t)NQKV * DIN * 2);
  float* biasP = (float*)alloc(NQKV * 4);
  u16*   qk    = (u16*)alloc((size_t)MTOT * 256 * 2);
  u16*   vT    = (u16*)alloc((size_t)BATCH * DV * SEQ * 2);
  u16*   P     = (u16*)alloc((size_t)BATCH * SEQ * SEQ * 2);
  if (off > ws_size) return;

  prep<<<dim3(6144 + 192), dim3(256), 0, stream>>>(x, xb, Wq, bq, Wk, bk, Wv, bv, WbT, biasP);

  // proj: [8192,1024] = xb @ WbT^T + bias; 128x256 tile, 3-slot ring
  gemm_proj<<<dim3(64 * 4), dim3(512), 0, stream>>>(xb, WbT, qk, vT, biasP);

  // P = exp(q_scaled @ k^T) per batch, 256x256 single-stage
  sgemm_exp<<<dim3(8 * 8 * BATCH), dim3(512), 0, stream>>>(qk, P);

  // out = (P @ vT^T) / rowsum(P) per batch, 128x192 tile (r8-proven)
  gemm_pv<<<dim3(16 * 4 * BATCH), dim3(512), 0, stream>>>(P, vT, out);
}

// Round 15
// 82.432 us; speedup vs baseline: 2.0172x; 1.0092x over previous
//
#include <hip/hip_runtime.h>
#include <stdint.h>

typedef unsigned short u16;
typedef __attribute__((ext_vector_type(8))) short short8;
typedef __attribute__((ext_vector_type(4))) float f32x4;

#define BATCH 4
#define SEQ   2048
#define DIN   768
#define DK    128
#define DV    768
#define MTOT  (BATCH*SEQ)   // 8192
#define NQKV  1024          // 128 q + 128 k + 768 v

__device__ __forceinline__ u16 f2bf(float f) {
  union { float f; uint32_t u; } v; v.f = f;
  uint32_t r = v.u + 0x7FFFu + ((v.u >> 16) & 1u);
  return (u16)(r >> 16);
}

template<int N> __device__ __forceinline__ void wait_vmcnt() {
  if constexpr (N == 0) asm volatile("s_waitcnt vmcnt(0)" ::: "memory");
  else if constexpr (N == 3) asm volatile("s_waitcnt vmcnt(3)" ::: "memory");
  else if constexpr (N == 5) asm volatile("s_waitcnt vmcnt(5)" ::: "memory");
  else if constexpr (N == 6) asm volatile("s_waitcnt vmcnt(6)" ::: "memory");
}

#define GLOAD_LDS(SRC, DST) \
  __builtin_amdgcn_global_load_lds( \
      (const __attribute__((address_space(1))) unsigned int*)(SRC), \
      (__attribute__((address_space(3))) unsigned int*)(DST), 16, 0, 0)

// ---------------- K0: prep = convert_x + pack weights/bias ----------------
__global__ __launch_bounds__(256) void prep(
    const float* __restrict__ x, u16* __restrict__ xb,
    const float* __restrict__ Wq, const float* __restrict__ bq,
    const float* __restrict__ Wk, const float* __restrict__ bk,
    const float* __restrict__ Wv, const float* __restrict__ bv,
    u16* __restrict__ WbT, float* __restrict__ biasP) {
  const float qs = 0.088388347648318447f;  // 1/sqrt(128)
  __shared__ u16 tile[64][72];
  int b = blockIdx.x;
  int tid = threadIdx.x;
  if (b < 6144) {               // convert x -> bf16
    int i = (b * 256 + tid) * 4;
    float4 v = *(const float4*)(x + i);
    u16 o[4] = { f2bf(v.x), f2bf(v.y), f2bf(v.z), f2bf(v.w) };
    *(uint2*)(xb + i) = *(const uint2*)o;
    return;
  }
  int bid2 = b - 6144;          // 0..191 : pack weights (12 x 16)
  int y   = bid2 / 12;
  int i0  = (bid2 - y * 12) * 64;
  const float* W; u16* dst; int ldw, nb; float sc;
  if (y < 2)      { W = Wq; dst = WbT;                      ldw = DK; sc = qs;   nb = y;     }
  else if (y < 4) { W = Wk; dst = WbT + (size_t)DK * DIN;   ldw = DK; sc = 1.0f; nb = y - 2; }
  else            { W = Wv; dst = WbT + (size_t)2*DK * DIN; ldw = DV; sc = 1.0f; nb = y - 4; }
  int n0 = nb * 64;
  if (i0 == 0 && y == 0) {
    for (int n = tid; n < NQKV; n += 256)
      biasP[n] = (n < DK) ? bq[n] * qs : (n < 2*DK ? bk[n - DK] : bv[n - 2*DK]);
  }
  int tr = tid >> 2;
  int tc = (tid & 3) * 16;
  const float* src = W + (size_t)(i0 + tr) * ldw + n0 + tc;
  u16 o[16];
#pragma unroll
  for (int u = 0; u < 16; u += 4) {
    float4 v = *(const float4*)(src + u);
    o[u] = f2bf(v.x * sc); o[u+1] = f2bf(v.y * sc); o[u+2] = f2bf(v.z * sc); o[u+3] = f2bf(v.w * sc);
  }
  *(uint4*)&tile[tr][tc]     = *(const uint4*)&o[0];
  *(uint4*)&tile[tr][tc + 8] = *(const uint4*)&o[8];
  __syncthreads();
  u16 tmp[16];
#pragma unroll
  for (int u = 0; u < 16; ++u) tmp[u] = tile[tc + u][tr];
  u16* d = dst + (size_t)(n0 + tr) * DIN + i0 + tc;
  *(uint4*)d       = *(const uint4*)&tmp[0];
  *(uint4*)(d + 8) = *(const uint4*)&tmp[8];
}

// ---------------- proj GEMM: 128x256 tile, 3-slot counted-vmcnt(6) ring ----------------
__global__ __launch_bounds__(512, 2) void gemm_proj(
    const u16* __restrict__ A, const u16* __restrict__ BT,
    u16* __restrict__ C0, u16* __restrict__ C1,
    const float* __restrict__ bias)
{
  const int NT = DIN / 64;             // 12 K-tiles
  __shared__ u16 As[3][128][64];       // 48 KB
  __shared__ u16 Bs[3][256][64];       // 96 KB
  const int tid = threadIdx.x;
  const int l   = tid & 63;
  const int wid = tid >> 6;
  const int wm  = wid >> 2;
  const int wn  = wid & 3;

  const int nwg = gridDim.x;           // 256
  const int cpx = nwg >> 3;
  const int bid = blockIdx.x;
  const int wg  = (bid & 7) * cpx + (bid >> 3);
  const int by  = wg >> 6;
  const int bx  = wg & 63;
  const int m0  = bx * 128;
  const int n0  = by * 256;

  f32x4 acc[4][4] = {};
  const int lr = l >> 3;
  const int lc = ((l & 7) ^ lr) * 8;

  auto STAGE = [&](int buf, int k0, int i0r, int i1r) {
#pragma unroll
    for (int i = 0; i < 6; ++i) {
      if (i < i0r || i >= i1r) continue;
      int c = wid * 6 + i;
      if (c < 16) {
        GLOAD_LDS(A + (size_t)(m0 + c * 8 + lr) * DIN + k0 + lc, &As[buf][c * 8][0]);
      } else {
        int cb = c - 16;
        GLOAD_LDS(BT + (size_t)(n0 + cb * 8 + lr) * DIN + k0 + lc, &Bs[buf][cb * 8][0]);
      }
    }
  };

  STAGE(0, 0, 0, 6);
  STAGE(1, 64, 0, 6);
  int cur = 0;
  for (int t = 0; t < NT; ++t) {
    if (t == NT - 1) wait_vmcnt<0>(); else wait_vmcnt<6>();
    __builtin_amdgcn_s_barrier();
    const int nxt2 = (cur + 2 >= 3) ? cur - 1 : cur + 2;
    const bool pf = (t + 2 < NT);
#pragma unroll
    for (int ks = 0; ks < 2; ++ks) {
      short8 af[4], bg[4];
#pragma unroll
      for (int i = 0; i < 4; ++i) {
        int row  = wm * 64 + i * 16 + (l & 15);
        int slot = (ks * 4 + (l >> 4)) ^ (row & 7);
        af[i] = *(const short8*)&As[cur][row][slot * 8];
      }
#pragma unroll
      for (int j = 0; j < 4; ++j) {
        int row  = wn * 64 + j * 16 + (l & 15);
        int slot = (ks * 4 + (l >> 4)) ^ (row & 7);
        bg[j] = *(const short8*)&Bs[cur][row][slot * 8];
      }
      if (pf) {
        if (ks == 0) STAGE(nxt2, (t + 2) * 64, 0, 3);
        else         STAGE(nxt2, (t + 2) * 64, 3, 6);
      }
      __builtin_amdgcn_s_setprio(1);
#pragma unroll
      for (int i = 0; i < 4; ++i)
#pragma unroll
        for (int j = 0; j < 4; ++j)
          acc[i][j] = __builtin_amdgcn_mfma_f32_16x16x32_bf16(af[i], bg[j], acc[i][j], 0, 0, 0);
      __builtin_amdgcn_s_setprio(0);
    }
    cur = (cur + 1 == 3) ? 0 : cur + 1;
  }

  const int rbase = (l >> 4) * 4;
  const int cl    = l & 15;
#pragma unroll
  for (int i = 0; i < 4; ++i) {
#pragma unroll
    for (int j = 0; j < 4; ++j) {
      int col  = n0 + wn * 64 + j * 16 + cl;
      int row0 = m0 + wm * 64 + i * 16 + rbase;
      float bv_ = bias[col];
      if (by == 0) {
#pragma unroll
        for (int q = 0; q < 4; ++q)
          C0[(size_t)(row0 + q) * 256 + col] = f2bf(acc[i][j][q] + bv_);
      } else {
        int b = row0 >> 11, t = row0 & 2047;
        u16 o[4];
#pragma unroll
        for (int q = 0; q < 4; ++q) o[q] = f2bf(acc[i][j][q] + bv_);
        *(uint2*)&C1[((size_t)b * DV + (col - 256)) * SEQ + t] = *(const uint2*)o;
      }
    }
  }
}

// ---------------- K3: S-GEMM 256x256: P_t = exp(q_s @ k^T) in FRAGMENT-TILED layout ----------------
// P_t[q16][t32][lane][8]: PV loads af fragments with one coalesced dwordx4.
// Repack via LDS (reuses As/Bs after compute); stores are 16B-coalesced.
__global__ __launch_bounds__(512, 2) void sgemm_exp(
    const u16* __restrict__ qk, u16* __restrict__ Pt)
{
  __shared__ u16 As[256][128];
  __shared__ u16 Bs[256][128];
  const int tid = threadIdx.x;
  const int l   = tid & 63;
  const int wid = tid >> 6;
  const int wm  = wid >> 2;            // 0..1 : 128-row half
  const int wn  = wid & 3;             // 0..3 : 64-col quarter

  const int nwg = gridDim.x;           // 256
  const int cpx = nwg >> 3;
  const int bid = blockIdx.x;
  const int wg  = (bid & 7) * cpx + (bid >> 3);
  const int z   = wg >> 6;
  const int rem = wg & 63;
  const int by  = rem >> 3;
  const int bx  = rem & 7;
  const int m0  = bx * 256;
  const int n0  = by * 256;

  const u16* A  = qk + (size_t)z * SEQ * 256;
  const u16* BT = qk + DK + (size_t)z * SEQ * 256;

  const int rin = l >> 4;
  const int s16 = l & 15;
#pragma unroll
  for (int i = 0; i < 16; ++i) {
    int c = wid * 16 + i;
    if (c < 64) {
      int r = c * 4 + rin;
      int gs = s16 ^ (r & 7);
      GLOAD_LDS(A + (size_t)(m0 + r) * 256 + gs * 8, &As[c * 4][0]);
    } else {
      int cb = c - 64;
      int r = cb * 4 + rin;
      int gs = s16 ^ (r & 7);
      GLOAD_LDS(BT + (size_t)(n0 + r) * 256 + gs * 8, &Bs[cb * 4][0]);
    }
  }
  __syncthreads();

  f32x4 acc[8][4] = {};
#pragma unroll
  for (int ks = 0; ks < 4; ++ks) {
    short8 af[8], bg[4];
#pragma unroll
    for (int i = 0; i < 8; ++i) {
      int row  = wm * 128 + i * 16 + (l & 15);
      int slot = (ks * 4 + (l >> 4)) ^ (row & 7);
      af[i] = *(const short8*)&As[row][slot * 8];
    }
#pragma unroll
    for (int j = 0; j < 4; ++j) {
      int row  = wn * 64 + j * 16 + (l & 15);
      int slot = (ks * 4 + (l >> 4)) ^ (row & 7);
      bg[j] = *(const short8*)&Bs[row][slot * 8];
    }
#pragma unroll
    for (int i = 0; i < 8; ++i)
#pragma unroll
      for (int j = 0; j < 4; ++j)
        acc[i][j] = __builtin_amdgcn_mfma_f32_16x16x32_bf16(af[i], bg[j], acc[i][j], 0, 0, 0);
  }

  __syncthreads();                     // done reading As/Bs; reuse as repack region
  // per-wave [128][64] region, XOR-swizzled 16B slots
  u16* region = (wid < 4) ? (&As[0][0] + wid * 8192) : (&Bs[0][0] + (wid - 4) * 8192);
#pragma unroll
  for (int i = 0; i < 8; ++i)
#pragma unroll
    for (int j = 0; j < 4; ++j)
#pragma unroll
      for (int q = 0; q < 4; ++q) {
        int lq  = i * 16 + (l >> 4) * 4 + q;
        int lt  = j * 16 + (l & 15);
        int col = (((lt >> 3) ^ (lq & 7)) << 3) | (lt & 7);
        region[lq * 64 + col] = f2bf(__expf(acc[i][j][q]));
      }
  __syncthreads();
  u16* Pz = (u16*)Pt + (size_t)z * SEQ * SEQ;
#pragma unroll
  for (int i = 0; i < 8; ++i)
#pragma unroll
    for (int jj = 0; jj < 2; ++jj) {
      int lq   = i * 16 + (l & 15);
      int slot = (jj * 4 + (l >> 4)) ^ (lq & 7);
      uint4 v  = *(const uint4*)&region[lq * 64 + slot * 8];
      int gq16 = (m0 >> 4) + wm * 8 + i;
      int gt32 = (n0 >> 5) + wn * 2 + jj;
      *(uint4*)&Pz[((size_t)(gq16 * 64 + gt32) * 64 + l) * 8] = v;
    }
}

// ---------------- PV GEMM: af direct-from-global (fragment-tiled P), B-only LDS ----------------
// out = (P @ vT^T) / rowsum(P); rowsum via ones-MFMA. 128x192 tile, 8 waves.
// B: 3-slot ring via global_load_lds (3/wave/tile). A: 8 coalesced dwordx4/wave/tile
// into double-buffered VGPRs. Per tile: wait vmcnt(3) retires AF(t)+B(t), B(t+2)
// stays in flight. Rule-18 sched_barrier after counted waits (asm loads feed MFMA).
__global__ __launch_bounds__(512, 2) void gemm_pv(
    const u16* __restrict__ Pt, const u16* __restrict__ vT,
    float* __restrict__ out)
{
  const int NT = SEQ / 64;             // 32
  __shared__ u16 Bs[3][192][64];       // 72 KB
  const int tid = threadIdx.x;
  const int l   = tid & 63;
  const int wid = tid >> 6;
  const int wm  = wid >> 2;            // 0..1
  const int wn  = wid & 3;             // 0..3

  const int nwg = gridDim.x;           // 256
  const int cpx = nwg >> 3;
  const int bid = blockIdx.x;
  const int wg  = (bid & 7) * cpx + (bid >> 3);
  const int z   = wg >> 6;
  const int rem = wg & 63;
  const int by  = rem / 16;
  const int bx  = rem & 15;
  const int m0  = bx * 128;
  const int n0  = by * 192;

  const u16* Ptz = Pt + (size_t)z * SEQ * SEQ;
  const u16* BT  = vT + (size_t)z * DV * SEQ;

  f32x4 acc[4][3] = {};
  f32x4 accO[4] = {};
  const short8 kOnes = {16256,16256,16256,16256,16256,16256,16256,16256};

  const int lr = l >> 3;
  const int lc = ((l & 7) ^ lr) * 8;

  auto STAGE_B = [&](int buf, int t0) {
#pragma unroll
    for (int i = 0; i < 3; ++i) {
      int c = wid * 3 + i;             // 0..23
      GLOAD_LDS(BT + (size_t)(n0 + c * 8 + lr) * SEQ + t0 * 64 + lc, &Bs[buf][c * 8][0]);
    }
  };

  uint4 afA[4][2], afB[4][2];
  auto AFLOAD = [&](uint4 (&dst)[4][2], int t) {
#pragma unroll
    for (int i = 0; i < 4; ++i)
#pragma unroll
      for (int ks = 0; ks < 2; ++ks) {
        const u16* p = Ptz + ((size_t)((bx * 8 + wm * 4 + i) * 64 + (2 * t + ks)) * 64 + l) * 8;
        asm volatile("global_load_dwordx4 %0, %1, off"
                     : "=v"(dst[i][ks]) : "v"(p) : "memory");
      }
  };

  auto BODY = [&](uint4 (&af)[4][2], uint4 (&afn)[4][2], int t) {
    if (t == NT - 1) wait_vmcnt<0>(); else wait_vmcnt<3>();
    __builtin_amdgcn_sched_barrier(0);
    __builtin_amdgcn_s_barrier();
    if (t + 1 < NT) AFLOAD(afn, t + 1);
    const int buf = t % 3;
#pragma unroll
    for (int ks = 0; ks < 2; ++ks) {
      short8 bg[3];
#pragma unroll
      for (int j = 0; j < 3; ++j) {
        int row  = wn * 48 + j * 16 + (l & 15);
        int slot = (ks * 4 + (l >> 4)) ^ (row & 7);
        bg[j] = *(const short8*)&Bs[buf][row][slot * 8];
      }
      __builtin_amdgcn_s_setprio(1);
#pragma unroll
      for (int i = 0; i < 4; ++i) {
        short8 a = *(const short8*)&af[i][ks];
#pragma unroll
        for (int j = 0; j < 3; ++j)
          acc[i][j] = __builtin_amdgcn_mfma_f32_16x16x32_bf16(a, bg[j], acc[i][j], 0, 0, 0);
        accO[i] = __builtin_amdgcn_mfma_f32_16x16x32_bf16(a, kOnes, accO[i], 0, 0, 0);
      }
      __builtin_amdgcn_s_setprio(0);
    }
    if (t + 2 < NT) STAGE_B((t + 2) % 3, t + 2);
    __builtin_amdgcn_s_barrier();
  };

  AFLOAD(afA, 0);                      // af first: FIFO -> vmcnt(3) retires AF0+B0
  STAGE_B(0, 0);
  STAGE_B(1, 1);
  for (int t = 0; t < NT; t += 2) {
    BODY(afA, afB, t);
    BODY(afB, afA, t + 1);
  }

  const int rbase = (l >> 4) * 4;
  const int cl    = l & 15;
#pragma unroll
  for (int i = 0; i < 4; ++i) {
    int row0 = m0 + wm * 64 + i * 16 + rbase;
    f32x4 rs;
#pragma unroll
    for (int q = 0; q < 4; ++q) rs[q] = 1.0f / accO[i][q];
#pragma unroll
    for (int j = 0; j < 3; ++j) {
      int col = n0 + wn * 48 + j * 16 + cl;
#pragma unroll
      for (int q = 0; q < 4; ++q)
        out[(size_t)z * SEQ * DV + (size_t)(row0 + q) * DV + col] = acc[i][j][q] * rs[q];
    }
  }
}

extern "C" void kernel_launch(void* const* d_in, const int* in_sizes, int n_in,
                              void* d_out, int out_size, void* d_ws, size_t ws_size,
                              hipStream_t stream) {
  const float* x  = (const float*)d_in[0];
  const float* Wq = (const float*)d_in[1];
  const float* bq = (const float*)d_in[2];
  const float* Wk = (const float*)d_in[3];
  const float* bk = (const float*)d_in[4];
  const float* Wv = (const float*)d_in[5];
  const float* bv = (const float*)d_in[6];
  float* out = (float*)d_out;

  size_t off = 0;
  auto alloc = [&](size_t bytes) -> void* {
    void* p = (char*)d_ws + off;
    off += (bytes + 255) & ~(size_t)255;
    return p;
  };
  u16*   xb    = (u16*)alloc((size_t)MTOT * DIN * 2);
  u16*   WbT   = (u16*)alloc((size_t)NQKV * DIN * 2);
  float* biasP = (float*)alloc(NQKV * 4);
  u16*   qk    = (u16*)alloc((size_t)MTOT * 256 * 2);
  u16*   vT    = (u16*)alloc((size_t)BATCH * DV * SEQ * 2);
  u16*   Pt    = (u16*)alloc((size_t)BATCH * SEQ * SEQ * 2);
  if (off > ws_size) return;

  prep<<<dim3(6144 + 192), dim3(256), 0, stream>>>(x, xb, Wq, bq, Wk, bk, Wv, bv, WbT, biasP);

  // proj: [8192,1024] = xb @ WbT^T + bias; 128x256 tile, 3-slot ring
  gemm_proj<<<dim3(64 * 4), dim3(512), 0, stream>>>(xb, WbT, qk, vT, biasP);

  // P_t = exp(q_scaled @ k^T) per batch, 256x256, fragment-tiled output
  sgemm_exp<<<dim3(8 * 8 * BATCH), dim3(512), 0, stream>>>(qk, Pt);

  // out = (P @ vT^T) / rowsum(P) per batch; af direct-from-global
  gemm_pv<<<dim3(16 * 4 * BATCH), dim3(512), 0, stream>>>(Pt, vT, out);
}